// Round 1
// baseline (787.936 us; speedup 1.0000x reference)
//
#include <hip/hip_runtime.h>

#define HW_TOT 131072
#define IMG_W  512
#define KC     2048
#define MAXKP  512
#define NB     32
#define NC     768
#define CG     48          // channels per sampler block
#define NCG    (NC / CG)   // 16

// ---------------------------------------------------------------------------
// K1: per-batch top-2048 (exact jax.lax.top_k semantics) + greedy NMS +
//     stable compaction. One 1024-thread block per batch image.
// ---------------------------------------------------------------------------
__global__ __launch_bounds__(1024) void detect_nms_kernel(
    const float* __restrict__ gray,
    const float* __restrict__ mask,
    float* __restrict__ out_kp,
    float* __restrict__ out_sc)
{
    const int b    = blockIdx.x;
    const int tid  = threadIdx.x;
    const int lane = tid & 63;
    const int wave = tid >> 6;

    const float* gi = gray + (size_t)b * HW_TOT;
    const float* mi = mask + (size_t)b * HW_TOT;

    __shared__ unsigned int       hist[16][257];   // per-wave histograms (padded: bank spread)
    __shared__ unsigned int       tot[256];
    __shared__ unsigned long long sel[KC];
    __shared__ unsigned int       eqidx[4096];
    __shared__ float              xs[KC], ys[KC], vsc[KC];
    __shared__ unsigned char      keep[KC];
    __shared__ int                scA[1024], scB[1024];
    __shared__ float              ssx[MAXKP], ssy[MAXKP], sss[MAXKP];
    __shared__ int                sh_digit, sh_krem;
    __shared__ unsigned int       cntA, cntE;

    // ---------- 4-pass MSB-first radix select on float bits ----------
    // (values are img*mask >= 0, so uint bit order == value order)
    unsigned int pivot = 0;
    int krem = KC;
    for (int pass = 0; pass < 4; ++pass) {
        const int shift = 24 - 8 * pass;
        for (int i = tid; i < 16 * 257; i += 1024) (&hist[0][0])[i] = 0u;
        __syncthreads();
        for (int e = tid; e < HW_TOT; e += 1024) {
            float v = gi[e] * mi[e];
            unsigned int fb = __float_as_uint(v);
            bool part = (pass == 0) || ((fb >> (shift + 8)) == (pivot >> (shift + 8)));
            if (part) atomicAdd(&hist[wave][(fb >> shift) & 255u], 1u);
        }
        __syncthreads();
        for (int d = tid; d < 256; d += 1024) {
            unsigned int s = 0;
            for (int w = 0; w < 16; ++w) s += hist[w][d];
            tot[d] = s;
        }
        __syncthreads();
        if (tid == 0) {
            int cum = 0, dsel = 0;
            for (int d = 255; d >= 1; --d) {
                int c = (int)tot[d];
                if (cum + c >= krem) { dsel = d; break; }
                cum += c;
            }
            sh_digit = dsel;
            sh_krem  = krem - cum;
        }
        __syncthreads();
        pivot |= ((unsigned int)sh_digit) << shift;
        krem = sh_krem;
        __syncthreads();
    }

    // ---------- compaction: fb > pivot always in; fb == pivot tie-break by index ----------
    if (tid == 0) { cntA = 0u; cntE = 0u; }
    __syncthreads();
    for (int e = tid; e < HW_TOT; e += 1024) {
        float v = gi[e] * mi[e];
        unsigned int fb = __float_as_uint(v);
        if (fb > pivot) {
            unsigned int p = atomicAdd(&cntA, 1u);
            sel[p] = ((unsigned long long)fb << 32) | (unsigned long long)(~(unsigned int)e);
        } else if (fb == pivot) {
            unsigned int p = atomicAdd(&cntE, 1u);
            if (p < 4096u) eqidx[p] = (unsigned int)e;
        }
    }
    __syncthreads();
    const unsigned int nA = cntA;
    const unsigned int nE = (cntE < 4096u) ? cntE : 4096u;
    for (int t = tid; t < (int)nE; t += 1024) {
        unsigned int mye = eqidx[t];
        int r = 0;
        for (unsigned int u = 0; u < nE; ++u) r += (eqidx[u] < mye) ? 1 : 0;
        if (r < krem)
            sel[nA + (unsigned int)r] =
                ((unsigned long long)pivot << 32) | (unsigned long long)(~mye);
    }
    __syncthreads();   // sel[0..2047] now holds exactly the top-2048 keys (unordered)

    // ---------- bitonic sort, descending (value desc, index asc) ----------
    for (unsigned int kk = 2; kk <= KC; kk <<= 1) {
        for (unsigned int j = kk >> 1; j > 0; j >>= 1) {
            for (unsigned int i = tid; i < KC; i += 1024) {
                unsigned int ixj = i ^ j;
                if (ixj > i) {
                    unsigned long long A = sel[i], Bv = sel[ixj];
                    bool descBlk = ((i & kk) == 0u);
                    bool sw = descBlk ? (A < Bv) : (A > Bv);
                    if (sw) { sel[i] = Bv; sel[ixj] = A; }
                }
            }
            __syncthreads();
        }
    }

    // ---------- unpack ----------
    for (int i = tid; i < KC; i += 1024) {
        unsigned long long key = sel[i];
        unsigned int fb = (unsigned int)(key >> 32);
        unsigned int e  = ~((unsigned int)(key & 0xFFFFFFFFull));
        float v = __uint_as_float(fb);
        vsc[i]  = v;
        xs[i]   = (float)(e & (IMG_W - 1));
        ys[i]   = (float)(e >> 9);
        keep[i] = (v > 0.1f) ? (unsigned char)1 : (unsigned char)0;
    }
    __syncthreads();

    // ---------- greedy NMS (exact sequential semantics), groups of 64 ----------
    for (int grp = 0; grp < KC / 64; ++grp) {
        const int i0 = grp * 64;
        if (wave == 0) {
            // wave-sequential inside the group
            float xi = xs[i0 + lane], yi = ys[i0 + lane];
            int kl = (int)keep[i0 + lane];
            for (int i = 0; i < 63; ++i) {
                int   ki = __shfl(kl, i);
                float xr = __shfl(xi, i);
                float yr = __shfl(yi, i);
                if (ki && lane > i) {
                    float dx = xi - xr, dy = yi - yr;
                    if (dx * dx + dy * dy < 9.0f) kl = 0;   // exact: integer coords
                }
            }
            keep[i0 + lane] = (unsigned char)kl;
        }
        __syncthreads();
        // group's final keepers suppress all later candidates in parallel
        for (int jj = i0 + 64 + tid; jj < KC; jj += 1024) {
            if (keep[jj]) {
                float xj = xs[jj], yj = ys[jj];
                int alive = 1;
                for (int i = i0; i < i0 + 64; ++i) {
                    if (keep[i]) {
                        float dx = xj - xs[i], dy = yj - ys[i];
                        if (dx * dx + dy * dy < 9.0f) { alive = 0; break; }
                    }
                }
                if (!alive) keep[jj] = 0;
            }
        }
        __syncthreads();
    }

    // ---------- stable compaction: rank of each kept candidate ----------
    int a0 = (int)keep[2 * tid];
    int a1 = (int)keep[2 * tid + 1];
    scA[tid] = a0 + a1;
    __syncthreads();
    int* src = scA; int* dst = scB;
    for (int off = 1; off < 1024; off <<= 1) {
        int v = src[tid];
        if (tid >= off) v += src[tid - off];
        dst[tid] = v;
        __syncthreads();
        int* t2 = src; src = dst; dst = t2;
    }
    int incl = src[tid];
    int exc  = incl - (a0 + a1);
    int r0 = exc, r1 = exc + a0;

    for (int p = tid; p < MAXKP; p += 1024) { ssx[p] = 0.f; ssy[p] = 0.f; sss[p] = 0.f; }
    __syncthreads();
    if (a0 && r0 < MAXKP) { ssx[r0] = xs[2*tid];     ssy[r0] = ys[2*tid];     sss[r0] = vsc[2*tid]; }
    if (a1 && r1 < MAXKP) { ssx[r1] = xs[2*tid + 1]; ssy[r1] = ys[2*tid + 1]; sss[r1] = vsc[2*tid + 1]; }
    __syncthreads();
    for (int p = tid; p < MAXKP; p += 1024) {
        out_kp[(size_t)b * (MAXKP * 2) + 2 * p    ] = ssx[p];
        out_kp[(size_t)b * (MAXKP * 2) + 2 * p + 1] = ssy[p];
        out_sc[(size_t)b * MAXKP + p]               = sss[p];
    }
}

// ---------------------------------------------------------------------------
// K2: bilinear descriptor sampling. Block = (batch, 48-channel group).
// Feature planes staged in LDS with stride 513 (bank-conflict-free).
// Reads kp coords straight from d_out (written by K1; zeros beyond n_keep
// reproduce the reference's fm[:,0,0] padding columns exactly).
// ---------------------------------------------------------------------------
__global__ __launch_bounds__(512) void sample_kernel(
    const float* __restrict__ fm,
    const float* __restrict__ kp,
    float* __restrict__ out_desc)
{
    const int blk = blockIdx.x;
    const int b   = blk >> 4;      // NCG = 16
    const int cg  = blk & 15;
    const int c0  = cg * CG;
    const int tid = threadIdx.x;

    __shared__ float L[CG * 513];
    __shared__ float sxl[MAXKP], syl[MAXKP];

    for (int e = tid; e < CG * 512; e += 512) {
        int cc = e >> 9, yx = e & 511;
        L[cc * 513 + yx] = fm[(size_t)b * NC * 512 + (size_t)(c0 + cc) * 512 + yx];
    }
    for (int p = tid; p < MAXKP; p += 512) {
        sxl[p] = kp[(size_t)b * (MAXKP * 2) + 2 * p];
        syl[p] = kp[(size_t)b * (MAXKP * 2) + 2 * p + 1];
    }
    __syncthreads();

    for (int e = tid; e < MAXKP * CG; e += 512) {
        int p  = e / CG;
        int cc = e - p * CG;
        float x = sxl[p], y = syl[p];
        float fx = x * (31.0f / 512.0f);   // == (x/512)*31 exactly (both exact in fp32)
        float fy = y * (15.0f / 256.0f);   // == (y/256)*15 exactly
        float x0f = floorf(fx), y0f = floorf(fy);
        float wx = fx - x0f, wy = fy - y0f;
        int x0 = (int)fminf(x0f,        31.f);
        int x1 = (int)fminf(x0f + 1.f,  31.f);
        int y0 = (int)fminf(y0f,        15.f);
        int y1 = (int)fminf(y0f + 1.f,  15.f);
        const float* Lc = &L[cc * 513];
        float p00 = Lc[y0 * 32 + x0];
        float p01 = Lc[y0 * 32 + x1];
        float p10 = Lc[y1 * 32 + x0];
        float p11 = Lc[y1 * 32 + x1];
        float d = p00 * (1.f - wx) * (1.f - wy)
                + p01 * wx        * (1.f - wy)
                + p10 * (1.f - wx) * wy
                + p11 * wx        * wy;
        out_desc[(size_t)b * MAXKP * NC + (size_t)p * NC + c0 + cc] = d;
    }
}

extern "C" void kernel_launch(void* const* d_in, const int* in_sizes, int n_in,
                              void* d_out, int out_size, void* d_ws, size_t ws_size,
                              hipStream_t stream)
{
    const float* gray = (const float*)d_in[0];
    const float* mask = (const float*)d_in[1];
    const float* fm   = (const float*)d_in[2];

    float* out      = (float*)d_out;
    float* out_kp   = out;                                        // (32,512,2)
    float* out_sc   = out + (size_t)NB * MAXKP * 2;               // (32,512)
    float* out_desc = out + (size_t)NB * MAXKP * 2
                          + (size_t)NB * MAXKP;                   // (32,512,768)

    detect_nms_kernel<<<NB, 1024, 0, stream>>>(gray, mask, out_kp, out_sc);
    sample_kernel<<<NB * NCG, 512, 0, stream>>>(fm, out_kp, out_desc);
}